// Round 6
// baseline (515.229 us; speedup 1.0000x reference)
//
#include <hip/hip_runtime.h>

// GHM Dice loss, 4 dispatches, zero global atomics, zero per-element LDS ops:
//  k_reduce1: chunked per-block partials {I,P,T} -> pws1      (reads p,t)
//  k_mid:     1-block reduce of pws1 -> ws[0]=2I/S, ws[1]=S
//  k_pass2:   chunked per-block partials {cnt[10],sm[10],tot} (reads p,t,lw)
//  k_final:   1-block reduce of pws2 -> loss
//
// Round-6 theory: r5 proved reduce1 is residency-independent (zero-FETCH L3
// replay = same 101 us) -> issue/latency-bound. Grid-stride + unroll keeps ~1
// guarded load-pair in flight (bounds checks block hoisting). Fix: fixed-trip
// chunks — each block owns exactly 256*K float4s, so the K-deep load loops
// have no guards and 16-24 global_load_dwordx4 issue back-to-back per thread.
// r4 already tested chunking but was contaminated (4096-block atomic tail in
// reduce1; per-element LDS RMW chains in pass2). Histogram stays in registers
// (r3-measured best), block-reduce via LDS transpose, partials via plain
// stores (r5-measured best).
//
// ws float layout (total ~460 KB, assumes ws_size >= 512 KB; r5 used 320 KB OK):
//   [0]=scale=2I/S  [1]=S                      (written by k_mid)
//   [OFF1 + blk*4 + {0,1,2}]  pws1 {I,P,T}     nb1 blocks
//   [OFF2 + blk*24 + s]       pws2 s=0..9 cnt, 10..19 sm, 20 vcount

constexpr int BINS = 10;
constexpr int K1   = 8;                  // float4 per thread, k_reduce1 (16 loads in flight)
constexpr int K2   = 8;                  // float4 per thread, k_pass2   (24 loads in flight)
constexpr int CH1  = 256 * K1;           // 2048 float4 per block
constexpr int CH2  = 256 * K2;
constexpr int OFF1 = 64;
constexpr int OFF2 = 16448;              // OFF1 + 4096*4

__global__ __launch_bounds__(256) void k_reduce1(const float4* __restrict__ p,
                                                 const float4* __restrict__ t,
                                                 float* __restrict__ ws,
                                                 int n4, int n) {
    const int chunk = blockIdx.x * CH1;
    const int base  = chunk + threadIdx.x;
    float sI = 0.f, sP = 0.f, sT = 0.f;

    if (chunk + CH1 <= n4) {             // full chunk: no guards, 16 loads in flight
        float4 pv[K1], tv[K1];
#pragma unroll
        for (int k = 0; k < K1; ++k) pv[k] = p[base + k * 256];
#pragma unroll
        for (int k = 0; k < K1; ++k) tv[k] = t[base + k * 256];
#pragma unroll
        for (int k = 0; k < K1; ++k) {
            sI += pv[k].x * tv[k].x + pv[k].y * tv[k].y + pv[k].z * tv[k].z + pv[k].w * tv[k].w;
            sP += pv[k].x + pv[k].y + pv[k].z + pv[k].w;
            sT += tv[k].x + tv[k].y + tv[k].z + tv[k].w;
        }
    } else {                             // ragged last chunk only
        for (int k = 0; k < K1; ++k) {
            int i = base + k * 256;
            if (i < n4) {
                float4 pv = p[i], tv = t[i];
                sI += pv.x * tv.x + pv.y * tv.y + pv.z * tv.z + pv.w * tv.w;
                sP += pv.x + pv.y + pv.z + pv.w;
                sT += tv.x + tv.y + tv.z + tv.w;
            }
        }
        if (blockIdx.x == gridDim.x - 1 && threadIdx.x == 0) {  // scalar tail (n % 4)
            const float* pf = (const float*)p;
            const float* tf = (const float*)t;
            for (int i = n4 * 4; i < n; ++i) { sI += pf[i] * tf[i]; sP += pf[i]; sT += tf[i]; }
        }
    }
#pragma unroll
    for (int o = 32; o > 0; o >>= 1) {
        sI += __shfl_down(sI, o);
        sP += __shfl_down(sP, o);
        sT += __shfl_down(sT, o);
    }
    __shared__ float rI[4], rP[4], rT[4];
    int wave = threadIdx.x >> 6, lane = threadIdx.x & 63;
    if (lane == 0) { rI[wave] = sI; rP[wave] = sP; rT[wave] = sT; }
    __syncthreads();
    if (threadIdx.x == 0) {              // plain stores — no atomics
        float* o = &ws[OFF1 + blockIdx.x * 4];
        o[0] = rI[0] + rI[1] + rI[2] + rI[3];
        o[1] = rP[0] + rP[1] + rP[2] + rP[3];
        o[2] = rT[0] + rT[1] + rT[2] + rT[3];
    }
}

__global__ __launch_bounds__(256) void k_mid(float* __restrict__ ws, int nb1) {
    __shared__ float red[256];
    int tid = threadIdx.x;
    int q = tid & 3, row = tid >> 2;     // 64 rows of threads, q=0..2 used
    float v = 0.f;
    if (q < 3)
        for (int b = row; b < nb1; b += 64) v += ws[OFF1 + b * 4 + q];
    red[tid] = v;
    __syncthreads();
    if (tid < 3) {
        float s = 0.f;
        for (int i = 0; i < 64; ++i) s += red[i * 4 + tid];
        red[tid] = s;
    }
    __syncthreads();
    if (tid == 0) {
        float I = red[0];
        float S = red[1] + red[2];
        ws[0] = 2.f * I / S;
        ws[1] = S;
    }
}

__global__ __launch_bounds__(256) void k_pass2(const float4* __restrict__ p,
                                               const float4* __restrict__ t,
                                               const float4* __restrict__ lw,
                                               float* __restrict__ ws,
                                               int n4, int n) {
    const float scale    = ws[0];        // 2I/S
    const float edge_top = 1.0f + 1e-6f;

    // Per-thread register histogram: all indexing compile-time -> stays in VGPRs.
    float cnt[BINS], sm[BINS];
#pragma unroll
    for (int b = 0; b < BINS; ++b) { cnt[b] = 0.f; sm[b] = 0.f; }
    float vcount = 0.f;

    auto process = [&](float pe, float te, float we) {
        bool valid = we > 0.f;
        vcount += valid ? 1.f : 0.f;
        float g = fabsf(scale * pe - te);
        bool inr = valid && (g < edge_top);
        int b = (int)(g * 10.f);          // g >= 0, trunc == floor
        b = b > (BINS - 1) ? (BINS - 1) : b;
        float addc = inr ? 1.f : 0.f;
        float adds = inr ? 2.f * pe * te : 0.f;
#pragma unroll
        for (int b0 = 0; b0 < BINS; ++b0) {
            bool m = (b == b0);
            cnt[b0] += m ? addc : 0.f;
            sm[b0]  += m ? adds : 0.f;
        }
    };

    const int chunk = blockIdx.x * CH2;
    const int base  = chunk + threadIdx.x;

    if (chunk + CH2 <= n4) {             // full chunk: 24 loads in flight
        float4 pv[K2], tv[K2], wv[K2];
#pragma unroll
        for (int k = 0; k < K2; ++k) pv[k] = p[base + k * 256];
#pragma unroll
        for (int k = 0; k < K2; ++k) tv[k] = t[base + k * 256];
#pragma unroll
        for (int k = 0; k < K2; ++k) wv[k] = lw[base + k * 256];
#pragma unroll
        for (int k = 0; k < K2; ++k) {
            process(pv[k].x, tv[k].x, wv[k].x);
            process(pv[k].y, tv[k].y, wv[k].y);
            process(pv[k].z, tv[k].z, wv[k].z);
            process(pv[k].w, tv[k].w, wv[k].w);
        }
    } else {
        for (int k = 0; k < K2; ++k) {
            int i = base + k * 256;
            if (i < n4) {
                float4 pv = p[i], tv = t[i], wv = lw[i];
                process(pv.x, tv.x, wv.x);
                process(pv.y, tv.y, wv.y);
                process(pv.z, tv.z, wv.z);
                process(pv.w, tv.w, wv.w);
            }
        }
        if (blockIdx.x == gridDim.x - 1 && threadIdx.x == 0) {  // scalar tail (n % 4)
            const float* pf = (const float*)p;
            const float* tf = (const float*)t;
            const float* wf = (const float*)lw;
            for (int i = n4 * 4; i < n; ++i) process(pf[i], tf[i], wf[i]);
        }
    }

    // Block reduction: LDS transpose, stride 21 (odd -> free 2-lane/bank aliasing).
    __shared__ float red[256 * 21];
    float* mine = &red[threadIdx.x * 21];
#pragma unroll
    for (int b0 = 0; b0 < BINS; ++b0) { mine[b0] = cnt[b0]; mine[BINS + b0] = sm[b0]; }
    mine[2 * BINS] = vcount;
    __syncthreads();

    int tid = threadIdx.x;
    if (tid < 2 * BINS + 1) {
        float v = 0.f;
        for (int i = 0; i < 256; ++i) v += red[i * 21 + tid];
        ws[OFF2 + blockIdx.x * 24 + tid] = v;   // plain store — no atomics
    }
}

__global__ __launch_bounds__(256) void k_final(const float* __restrict__ ws,
                                               float* __restrict__ out, int nb2) {
    __shared__ float red[256];
    __shared__ float fin[24];
    int tid  = threadIdx.x;
    int grp  = tid / 24;                 // 10 groups of 24 threads (tid < 240)
    int slot = tid - grp * 24;           // 0..23, slots 0..20 used
    float v = 0.f;
    if (tid < 240 && slot <= 2 * BINS)
        for (int b = grp; b < nb2; b += 10) v += ws[OFF2 + b * 24 + slot];
    red[tid] = v;
    __syncthreads();
    if (tid <= 2 * BINS) {
        float s = 0.f;
#pragma unroll
        for (int g = 0; g < 10; ++g) s += red[g * 24 + tid];
        fin[tid] = s;
    }
    __syncthreads();
    if (tid == 0) {
        float S   = ws[1];
        float tot = fmaxf(fin[20], 1.0f);
        int nne = 0;
        for (int b = 0; b < BINS; ++b) nne += (fin[b] > 0.f) ? 1 : 0;
        float nn = fmaxf((float)nne, 1.0f);
        float wsum = 0.f;
        for (int b = 0; b < BINS; ++b) {
            float c = fmaxf(fin[b], 1.0f);
            wsum += fin[BINS + b] * (tot / c);   // fin[10+b] carries sum of 2*p*t
        }
        wsum /= nn;
        out[0] = 1.0f - wsum / S;
    }
}

extern "C" void kernel_launch(void* const* d_in, const int* in_sizes, int n_in,
                              void* d_out, int out_size, void* d_ws, size_t ws_size,
                              hipStream_t stream) {
    const float* p  = (const float*)d_in[0];
    const float* t  = (const float*)d_in[1];
    const float* lw = (const float*)d_in[2];
    float* ws  = (float*)d_ws;
    float* out = (float*)d_out;
    int n  = in_sizes[0];
    int n4 = n >> 2;

    int nb1 = (n4 + CH1 - 1) / CH1;      // 4096 at N=33.5M
    int nb2 = (n4 + CH2 - 1) / CH2;      // 4096
    if (nb1 < 1) nb1 = 1;
    if (nb2 < 1) nb2 = 1;

    k_reduce1<<<nb1, 256, 0, stream>>>((const float4*)p, (const float4*)t, ws, n4, n);
    k_mid<<<1, 256, 0, stream>>>(ws, nb1);
    k_pass2<<<nb2, 256, 0, stream>>>((const float4*)p, (const float4*)t,
                                     (const float4*)lw, ws, n4, n);
    k_final<<<1, 256, 0, stream>>>(ws, out, nb2);
}

// Round 7
// 408.340 us; speedup vs baseline: 1.2618x; 1.2618x over previous
//
#include <hip/hip_runtime.h>

// GHM Dice loss, 4 dispatches, zero global atomics, zero per-element LDS ops:
//  k_reduce1: chunked per-block partials {I,P,T} -> pws1      (reads p,t)
//  k_mid:     1-block MLP reduce of pws1 -> ws[0]=2I/S, ws[1]=S
//  k_pass2:   chunked per-block partials {cnt[10],sm[10],tot} (reads p,t,lw)
//  k_final:   1-block MLP reduce of pws2 -> loss
//
// Round-7: r6 exposed k_final as the #1 dispatch (113 us): one block, each
// thread doing ~410 SERIAL dependent global loads (dynamic-bound loop -> ~1
// load in flight x ~700 cyc latency; counters: 0.02% BW, 0.01% VALU = pure
// latency stall). Fix: per-thread unrolled float4 record loads (6 independent
// loads per 24-float record, compile-time slot mapping) + LDS transpose.
// Same for k_mid (1 float4 per record). reduce1/pass2 left byte-identical to
// r6 so their clean counters surface in top-5 next round.
//
// ws float layout:
//   [0]=scale=2I/S  [1]=S                      (written by k_mid)
//   [OFF1 + blk*4 + {0,1,2}]   pws1 {I,P,T}    (slot 3 pad, stays poisoned)
//   [OFF2 + blk*24 + s]        pws2 s=0..9 cnt, 10..19 sm, 20 vcount
//                                              (slots 21..23 pad, poisoned)

constexpr int BINS = 10;
constexpr int K1   = 8;                  // float4 per thread, k_reduce1
constexpr int K2   = 8;                  // float4 per thread, k_pass2
constexpr int CH1  = 256 * K1;           // 2048 float4 per block
constexpr int CH2  = 256 * K2;
constexpr int OFF1 = 64;
constexpr int OFF2 = 16448;              // OFF1 + 4096*4

__global__ __launch_bounds__(256) void k_reduce1(const float4* __restrict__ p,
                                                 const float4* __restrict__ t,
                                                 float* __restrict__ ws,
                                                 int n4, int n) {
    const int chunk = blockIdx.x * CH1;
    const int base  = chunk + threadIdx.x;
    float sI = 0.f, sP = 0.f, sT = 0.f;

    if (chunk + CH1 <= n4) {             // full chunk: no guards, 16 loads in flight
        float4 pv[K1], tv[K1];
#pragma unroll
        for (int k = 0; k < K1; ++k) pv[k] = p[base + k * 256];
#pragma unroll
        for (int k = 0; k < K1; ++k) tv[k] = t[base + k * 256];
#pragma unroll
        for (int k = 0; k < K1; ++k) {
            sI += pv[k].x * tv[k].x + pv[k].y * tv[k].y + pv[k].z * tv[k].z + pv[k].w * tv[k].w;
            sP += pv[k].x + pv[k].y + pv[k].z + pv[k].w;
            sT += tv[k].x + tv[k].y + tv[k].z + tv[k].w;
        }
    } else {                             // ragged last chunk only
        for (int k = 0; k < K1; ++k) {
            int i = base + k * 256;
            if (i < n4) {
                float4 pv = p[i], tv = t[i];
                sI += pv.x * tv.x + pv.y * tv.y + pv.z * tv.z + pv.w * tv.w;
                sP += pv.x + pv.y + pv.z + pv.w;
                sT += tv.x + tv.y + tv.z + tv.w;
            }
        }
    }
    if (blockIdx.x == 0 && threadIdx.x == 0) {   // scalar tail (n % 4), always checked
        const float* pf = (const float*)p;
        const float* tf = (const float*)t;
        for (int i = n4 * 4; i < n; ++i) { sI += pf[i] * tf[i]; sP += pf[i]; sT += tf[i]; }
    }
#pragma unroll
    for (int o = 32; o > 0; o >>= 1) {
        sI += __shfl_down(sI, o);
        sP += __shfl_down(sP, o);
        sT += __shfl_down(sT, o);
    }
    __shared__ float rI[4], rP[4], rT[4];
    int wave = threadIdx.x >> 6, lane = threadIdx.x & 63;
    if (lane == 0) { rI[wave] = sI; rP[wave] = sP; rT[wave] = sT; }
    __syncthreads();
    if (threadIdx.x == 0) {              // plain stores — no atomics
        float* o = &ws[OFF1 + blockIdx.x * 4];
        o[0] = rI[0] + rI[1] + rI[2] + rI[3];
        o[1] = rP[0] + rP[1] + rP[2] + rP[3];
        o[2] = rT[0] + rT[1] + rT[2] + rT[3];
    }
}

// 1-block reduce of pws1: each thread loads its records as independent float4s
// (16 in flight at nb1=4096), LDS reduce, write scale & S.
__global__ __launch_bounds__(256) void k_mid(float* __restrict__ ws, int nb1) {
    const float4* pws = (const float4*)&ws[OFF1];
    float aI = 0.f, aP = 0.f, aT = 0.f;
    for (int b = threadIdx.x; b < nb1; b += 256) {   // independent iterations
        float4 v = pws[b];                            // slot 3 = pad (ignored)
        aI += v.x; aP += v.y; aT += v.z;
    }
    __shared__ float red[256 * 5];
    float* mine = &red[threadIdx.x * 5];              // stride 5: odd, conflict-free
    mine[0] = aI; mine[1] = aP; mine[2] = aT;
    __syncthreads();
    int tid = threadIdx.x;
    if (tid < 3) {
        float s = 0.f;
        for (int i = 0; i < 256; ++i) s += red[i * 5 + tid];
        red[tid] = s;
    }
    __syncthreads();
    if (tid == 0) {
        float I = red[0];
        float S = red[1] + red[2];
        ws[0] = 2.f * I / S;
        ws[1] = S;
    }
}

__global__ __launch_bounds__(256) void k_pass2(const float4* __restrict__ p,
                                               const float4* __restrict__ t,
                                               const float4* __restrict__ lw,
                                               float* __restrict__ ws,
                                               int n4, int n) {
    const float scale    = ws[0];        // 2I/S
    const float edge_top = 1.0f + 1e-6f;

    // Per-thread register histogram: all indexing compile-time -> stays in VGPRs.
    float cnt[BINS], sm[BINS];
#pragma unroll
    for (int b = 0; b < BINS; ++b) { cnt[b] = 0.f; sm[b] = 0.f; }
    float vcount = 0.f;

    auto process = [&](float pe, float te, float we) {
        bool valid = we > 0.f;
        vcount += valid ? 1.f : 0.f;
        float g = fabsf(scale * pe - te);
        bool inr = valid && (g < edge_top);
        int b = (int)(g * 10.f);          // g >= 0, trunc == floor
        b = b > (BINS - 1) ? (BINS - 1) : b;
        float addc = inr ? 1.f : 0.f;
        float adds = inr ? 2.f * pe * te : 0.f;
#pragma unroll
        for (int b0 = 0; b0 < BINS; ++b0) {
            bool m = (b == b0);
            cnt[b0] += m ? addc : 0.f;
            sm[b0]  += m ? adds : 0.f;
        }
    };

    const int chunk = blockIdx.x * CH2;
    const int base  = chunk + threadIdx.x;

    if (chunk + CH2 <= n4) {             // full chunk: 24 loads in flight
        float4 pv[K2], tv[K2], wv[K2];
#pragma unroll
        for (int k = 0; k < K2; ++k) pv[k] = p[base + k * 256];
#pragma unroll
        for (int k = 0; k < K2; ++k) tv[k] = t[base + k * 256];
#pragma unroll
        for (int k = 0; k < K2; ++k) wv[k] = lw[base + k * 256];
#pragma unroll
        for (int k = 0; k < K2; ++k) {
            process(pv[k].x, tv[k].x, wv[k].x);
            process(pv[k].y, tv[k].y, wv[k].y);
            process(pv[k].z, tv[k].z, wv[k].z);
            process(pv[k].w, tv[k].w, wv[k].w);
        }
    } else {
        for (int k = 0; k < K2; ++k) {
            int i = base + k * 256;
            if (i < n4) {
                float4 pv = p[i], tv = t[i], wv = lw[i];
                process(pv.x, tv.x, wv.x);
                process(pv.y, tv.y, wv.y);
                process(pv.z, tv.z, wv.z);
                process(pv.w, tv.w, wv.w);
            }
        }
    }
    if (blockIdx.x == 0 && threadIdx.x == 0) {   // scalar tail (n % 4), always checked
        const float* pf = (const float*)p;
        const float* tf = (const float*)t;
        const float* wf = (const float*)lw;
        for (int i = n4 * 4; i < n; ++i) process(pf[i], tf[i], wf[i]);
    }

    // Block reduction: LDS transpose, stride 21 (odd -> free 2-lane/bank aliasing).
    __shared__ float red[256 * 21];
    float* mine = &red[threadIdx.x * 21];
#pragma unroll
    for (int b0 = 0; b0 < BINS; ++b0) { mine[b0] = cnt[b0]; mine[BINS + b0] = sm[b0]; }
    mine[2 * BINS] = vcount;
    __syncthreads();

    int tid = threadIdx.x;
    if (tid < 2 * BINS + 1) {
        float v = 0.f;
        for (int i = 0; i < 256; ++i) v += red[i * 21 + tid];
        ws[OFF2 + blockIdx.x * 24 + tid] = v;   // plain store — no atomics
    }
}

// 1-block reduce of pws2: each 24-float record = 6 aligned float4s; every
// thread accumulates its records with 6 independent loads each (all slot
// indexing compile-time), then LDS transpose. Pad slots 21..23 are loaded
// (poisoned but finite floats) and discarded.
__global__ __launch_bounds__(256) void k_final(const float* __restrict__ ws,
                                               float* __restrict__ out, int nb2) {
    float acc[24];
#pragma unroll
    for (int s = 0; s < 24; ++s) acc[s] = 0.f;

    for (int b = threadIdx.x; b < nb2; b += 256) {   // independent iterations
        const float4* rec = (const float4*)&ws[OFF2 + b * 24];
        float4 v0 = rec[0], v1 = rec[1], v2 = rec[2],
               v3 = rec[3], v4 = rec[4], v5 = rec[5];
        acc[0]  += v0.x; acc[1]  += v0.y; acc[2]  += v0.z; acc[3]  += v0.w;
        acc[4]  += v1.x; acc[5]  += v1.y; acc[6]  += v1.z; acc[7]  += v1.w;
        acc[8]  += v2.x; acc[9]  += v2.y; acc[10] += v2.z; acc[11] += v2.w;
        acc[12] += v3.x; acc[13] += v3.y; acc[14] += v3.z; acc[15] += v3.w;
        acc[16] += v4.x; acc[17] += v4.y; acc[18] += v4.z; acc[19] += v4.w;
        acc[20] += v5.x;  // 21..23 are pad — not accumulated
    }

    __shared__ float red[256 * 25];                  // stride 25: odd, conflict-free
    float* mine = &red[threadIdx.x * 25];
#pragma unroll
    for (int s = 0; s <= 2 * BINS; ++s) mine[s] = acc[s];
    __syncthreads();

    __shared__ float fin[24];
    int tid = threadIdx.x;
    if (tid <= 2 * BINS) {
        float s = 0.f;
        for (int i = 0; i < 256; ++i) s += red[i * 25 + tid];
        fin[tid] = s;
    }
    __syncthreads();
    if (tid == 0) {
        float S   = ws[1];
        float tot = fmaxf(fin[20], 1.0f);
        int nne = 0;
        for (int b = 0; b < BINS; ++b) nne += (fin[b] > 0.f) ? 1 : 0;
        float nn = fmaxf((float)nne, 1.0f);
        float wsum = 0.f;
        for (int b = 0; b < BINS; ++b) {
            float c = fmaxf(fin[b], 1.0f);
            wsum += fin[BINS + b] * (tot / c);   // fin[10+b] carries sum of 2*p*t
        }
        wsum /= nn;
        out[0] = 1.0f - wsum / S;
    }
}

extern "C" void kernel_launch(void* const* d_in, const int* in_sizes, int n_in,
                              void* d_out, int out_size, void* d_ws, size_t ws_size,
                              hipStream_t stream) {
    const float* p  = (const float*)d_in[0];
    const float* t  = (const float*)d_in[1];
    const float* lw = (const float*)d_in[2];
    float* ws  = (float*)d_ws;
    float* out = (float*)d_out;
    int n  = in_sizes[0];
    int n4 = n >> 2;

    int nb1 = (n4 + CH1 - 1) / CH1;      // 4096 at N=33.5M
    int nb2 = (n4 + CH2 - 1) / CH2;      // 4096
    if (nb1 < 1) nb1 = 1;
    if (nb2 < 1) nb2 = 1;

    k_reduce1<<<nb1, 256, 0, stream>>>((const float4*)p, (const float4*)t, ws, n4, n);
    k_mid<<<1, 256, 0, stream>>>(ws, nb1);
    k_pass2<<<nb2, 256, 0, stream>>>((const float4*)p, (const float4*)t,
                                     (const float4*)lw, ws, n4, n);
    k_final<<<1, 256, 0, stream>>>(ws, out, nb2);
}

// Round 8
// 401.328 us; speedup vs baseline: 1.2838x; 1.0175x over previous
//
#include <hip/hip_runtime.h>

// GHM Dice loss, 4 dispatches, zero global atomics, zero per-element LDS ops:
//  k_reduce1: persistent-loop per-block partials {I,P,T}      (reads p,t)
//  k_mid:     1-block MLP reduce of pws1 -> ws[0]=2I/S, ws[1]=S
//  k_pass2:   persistent-loop partials {cnt[10],sm[10],tot}   (reads p,t,lw)
//  k_final:   1-block MLP reduce of pws2 -> loss
//
// Round-8 theory: r7's one-shot blocks issue their loads ONCE then idle
// through a ~50K-cycle tail/teardown — load-queue duty cycle is the limiter
// (reduce1 2.7 TB/s vs pass2 4.1 TB/s scales with in-flight loads; m13's
// LOOPING copy kernel hits 6.3 TB/s). Fix: 2048 persistent blocks looping
// block-strided over chunks; inner K=4 load batch is unguarded (scalar loop
// condition only), so 8-12 loads stream back-to-back every iteration and the
// tail runs once per block. pass2 also trims VALU: int counts via addc idiom,
// dummy-slot (10) kills the per-bin validity cndmask, fabs folded into
// consumers as input modifiers.
//
// ws float layout:
//   [0]=scale=2I/S  [1]=S                      (written by k_mid)
//   [OFF1 + blk*4 + {0,1,2}]   pws1 {I,P,T}    (slot 3 pad, poisoned, ignored)
//   [OFF2 + blk*24 + s]        pws2 s=0..9 cnt, 10..19 sm, 20 vcount
//                                              (slots 21..23 pad, ignored)

constexpr int BINS   = 10;
constexpr int K      = 4;                // float4 per thread per chunk
constexpr int CH     = 256 * K;          // 1024 float4 per chunk
constexpr int BLOCKS = 2048;             // 8 blocks/CU, persistent
constexpr int OFF1   = 64;
constexpr int OFF2   = 16448;

__global__ __launch_bounds__(256) void k_reduce1(const float4* __restrict__ p,
                                                 const float4* __restrict__ t,
                                                 float* __restrict__ ws,
                                                 int n4, int n) {
    const int tid   = threadIdx.x;
    const int nfull = n4 / CH;           // full chunks (8192 at N=33.5M)
    float sI = 0.f, sP = 0.f, sT = 0.f;

    for (int c = blockIdx.x; c < nfull; c += gridDim.x) {   // scalar loop cond
        const int base = c * CH + tid;
        float4 pv[K], tv[K];
#pragma unroll
        for (int k = 0; k < K; ++k) pv[k] = p[base + k * 256];  // 8 loads
#pragma unroll
        for (int k = 0; k < K; ++k) tv[k] = t[base + k * 256];  // back-to-back
#pragma unroll
        for (int k = 0; k < K; ++k) {
            sI += pv[k].x * tv[k].x + pv[k].y * tv[k].y + pv[k].z * tv[k].z + pv[k].w * tv[k].w;
            sP += pv[k].x + pv[k].y + pv[k].z + pv[k].w;
            sT += tv[k].x + tv[k].y + tv[k].z + tv[k].w;
        }
    }
    if (blockIdx.x == 0) {               // float4 remainder (n4 % CH)
        for (int i = nfull * CH + tid; i < n4; i += 256) {
            float4 pv = p[i], tv = t[i];
            sI += pv.x * tv.x + pv.y * tv.y + pv.z * tv.z + pv.w * tv.w;
            sP += pv.x + pv.y + pv.z + pv.w;
            sT += tv.x + tv.y + tv.z + tv.w;
        }
        if (tid == 0) {                  // scalar tail (n % 4)
            const float* pf = (const float*)p;
            const float* tf = (const float*)t;
            for (int i = n4 * 4; i < n; ++i) { sI += pf[i] * tf[i]; sP += pf[i]; sT += tf[i]; }
        }
    }
#pragma unroll
    for (int o = 32; o > 0; o >>= 1) {
        sI += __shfl_down(sI, o);
        sP += __shfl_down(sP, o);
        sT += __shfl_down(sT, o);
    }
    __shared__ float rI[4], rP[4], rT[4];
    int wave = tid >> 6, lane = tid & 63;
    if (lane == 0) { rI[wave] = sI; rP[wave] = sP; rT[wave] = sT; }
    __syncthreads();
    if (tid == 0) {                      // plain stores — no atomics
        float* o = &ws[OFF1 + blockIdx.x * 4];
        o[0] = rI[0] + rI[1] + rI[2] + rI[3];
        o[1] = rP[0] + rP[1] + rP[2] + rP[3];
        o[2] = rT[0] + rT[1] + rT[2] + rT[3];
    }
}

// 1-block reduce of pws1 (2048 records): independent float4 loads + LDS reduce.
__global__ __launch_bounds__(256) void k_mid(float* __restrict__ ws, int nb1) {
    const float4* pws = (const float4*)&ws[OFF1];
    float aI = 0.f, aP = 0.f, aT = 0.f;
    for (int b = threadIdx.x; b < nb1; b += 256) {   // independent iterations
        float4 v = pws[b];                            // slot 3 = pad (ignored)
        aI += v.x; aP += v.y; aT += v.z;
    }
    __shared__ float red[256 * 5];
    float* mine = &red[threadIdx.x * 5];              // odd stride: conflict-free
    mine[0] = aI; mine[1] = aP; mine[2] = aT;
    __syncthreads();
    int tid = threadIdx.x;
    if (tid < 3) {
        float s = 0.f;
        for (int i = 0; i < 256; ++i) s += red[i * 5 + tid];
        red[tid] = s;
    }
    __syncthreads();
    if (tid == 0) {
        float I = red[0];
        float S = red[1] + red[2];
        ws[0] = 2.f * I / S;
        ws[1] = S;
    }
}

__global__ __launch_bounds__(256) void k_pass2(const float4* __restrict__ p,
                                               const float4* __restrict__ t,
                                               const float4* __restrict__ lw,
                                               float* __restrict__ ws,
                                               int n4, int n) {
    const float scale    = ws[0];        // 2I/S
    const float edge_top = 1.0f + 1e-6f;
    const int tid   = threadIdx.x;
    const int nfull = n4 / CH;

    // Per-thread register histogram; compile-time indexing -> VGPRs.
    int   cnt[BINS];
    float sm[BINS];
#pragma unroll
    for (int b = 0; b < BINS; ++b) { cnt[b] = 0; sm[b] = 0.f; }
    int vcount = 0;

    auto process = [&](float pe, float te, float we) {
        bool valid = we > 0.f;
        vcount += valid;                          // int addc
        float g = fabsf(scale * pe - te);         // fma; abs folds into consumers
        bool inr = valid && (g < edge_top);
        int b = (int)(g * 10.f);                  // g >= 0, trunc == floor
        b = b > (BINS - 1) ? (BINS - 1) : b;
        int slot = inr ? b : BINS;                // dummy slot 10: no masked adds needed
        float adds = 2.f * pe * te;
#pragma unroll
        for (int b0 = 0; b0 < BINS; ++b0) {
            bool m = (slot == b0);
            cnt[b0] += m;                         // cmp + addc
            sm[b0]  += m ? adds : 0.f;            // cndmask + add
        }
    };

    for (int c = blockIdx.x; c < nfull; c += gridDim.x) {   // scalar loop cond
        const int base = c * CH + tid;
        float4 pv[K], tv[K], wv[K];
#pragma unroll
        for (int k = 0; k < K; ++k) pv[k] = p[base + k * 256];   // 12 loads
#pragma unroll
        for (int k = 0; k < K; ++k) tv[k] = t[base + k * 256];   // back-to-back
#pragma unroll
        for (int k = 0; k < K; ++k) wv[k] = lw[base + k * 256];
#pragma unroll
        for (int k = 0; k < K; ++k) {
            process(pv[k].x, tv[k].x, wv[k].x);
            process(pv[k].y, tv[k].y, wv[k].y);
            process(pv[k].z, tv[k].z, wv[k].z);
            process(pv[k].w, tv[k].w, wv[k].w);
        }
    }
    if (blockIdx.x == 0) {               // float4 remainder (n4 % CH)
        for (int i = nfull * CH + tid; i < n4; i += 256) {
            float4 pv = p[i], tv = t[i], wv = lw[i];
            process(pv.x, tv.x, wv.x);
            process(pv.y, tv.y, wv.y);
            process(pv.z, tv.z, wv.z);
            process(pv.w, tv.w, wv.w);
        }
        if (tid == 0) {                  // scalar tail (n % 4)
            const float* pf = (const float*)p;
            const float* tf = (const float*)t;
            const float* wf = (const float*)lw;
            for (int i = n4 * 4; i < n; ++i) process(pf[i], tf[i], wf[i]);
        }
    }

    // Block reduction: LDS transpose, odd stride 21 -> free 2-lane/bank aliasing.
    __shared__ float red[256 * 21];
    float* mine = &red[tid * 21];
#pragma unroll
    for (int b0 = 0; b0 < BINS; ++b0) {
        mine[b0]        = (float)cnt[b0];
        mine[BINS + b0] = sm[b0];
    }
    mine[2 * BINS] = (float)vcount;
    __syncthreads();

    if (tid < 2 * BINS + 1) {
        float v = 0.f;
        for (int i = 0; i < 256; ++i) v += red[i * 21 + tid];
        ws[OFF2 + blockIdx.x * 24 + tid] = v;   // plain store — no atomics
    }
}

// 1-block reduce of pws2: 24-float records = 6 aligned float4s, 6 independent
// loads per record per thread, then LDS transpose. Pad slots discarded.
__global__ __launch_bounds__(256) void k_final(const float* __restrict__ ws,
                                               float* __restrict__ out, int nb2) {
    float acc[24];
#pragma unroll
    for (int s = 0; s < 24; ++s) acc[s] = 0.f;

    for (int b = threadIdx.x; b < nb2; b += 256) {   // independent iterations
        const float4* rec = (const float4*)&ws[OFF2 + b * 24];
        float4 v0 = rec[0], v1 = rec[1], v2 = rec[2],
               v3 = rec[3], v4 = rec[4], v5 = rec[5];
        acc[0]  += v0.x; acc[1]  += v0.y; acc[2]  += v0.z; acc[3]  += v0.w;
        acc[4]  += v1.x; acc[5]  += v1.y; acc[6]  += v1.z; acc[7]  += v1.w;
        acc[8]  += v2.x; acc[9]  += v2.y; acc[10] += v2.z; acc[11] += v2.w;
        acc[12] += v3.x; acc[13] += v3.y; acc[14] += v3.z; acc[15] += v3.w;
        acc[16] += v4.x; acc[17] += v4.y; acc[18] += v4.z; acc[19] += v4.w;
        acc[20] += v5.x;  // 21..23 pad — not accumulated
    }

    __shared__ float red[256 * 25];                  // odd stride: conflict-free
    float* mine = &red[threadIdx.x * 25];
#pragma unroll
    for (int s = 0; s <= 2 * BINS; ++s) mine[s] = acc[s];
    __syncthreads();

    __shared__ float fin[24];
    int tid = threadIdx.x;
    if (tid <= 2 * BINS) {
        float s = 0.f;
        for (int i = 0; i < 256; ++i) s += red[i * 25 + tid];
        fin[tid] = s;
    }
    __syncthreads();
    if (tid == 0) {
        float S   = ws[1];
        float tot = fmaxf(fin[20], 1.0f);
        int nne = 0;
        for (int b = 0; b < BINS; ++b) nne += (fin[b] > 0.f) ? 1 : 0;
        float nn = fmaxf((float)nne, 1.0f);
        float wsum = 0.f;
        for (int b = 0; b < BINS; ++b) {
            float c = fmaxf(fin[b], 1.0f);
            wsum += fin[BINS + b] * (tot / c);   // fin[10+b] carries sum of 2*p*t
        }
        wsum /= nn;
        out[0] = 1.0f - wsum / S;
    }
}

extern "C" void kernel_launch(void* const* d_in, const int* in_sizes, int n_in,
                              void* d_out, int out_size, void* d_ws, size_t ws_size,
                              hipStream_t stream) {
    const float* p  = (const float*)d_in[0];
    const float* t  = (const float*)d_in[1];
    const float* lw = (const float*)d_in[2];
    float* ws  = (float*)d_ws;
    float* out = (float*)d_out;
    int n  = in_sizes[0];
    int n4 = n >> 2;

    k_reduce1<<<BLOCKS, 256, 0, stream>>>((const float4*)p, (const float4*)t, ws, n4, n);
    k_mid<<<1, 256, 0, stream>>>(ws, BLOCKS);
    k_pass2<<<BLOCKS, 256, 0, stream>>>((const float4*)p, (const float4*)t,
                                        (const float4*)lw, ws, n4, n);
    k_final<<<1, 256, 0, stream>>>(ws, out, BLOCKS);
}